// Round 4
// baseline (285.002 us; speedup 1.0000x reference)
//
#include <hip/hip_runtime.h>
#include <hip/hip_fp16.h>

// v: (N=2, C=3, D=128, H=128, W=128) float32.
// d_out: transformation (2,3,128^3) then disp_vox (2,3,128^3), float32, flat.
#define DHW   (1 << 21)          // 128^3
#define CDHW  (3 * DHW)
#define NCDHW (2 * CDHW)
#define NVOX  (2 * DHW)          // N * D*H*W
#define NBLK  (NVOX / 256)       // 16384 step-kernel blocks

// Displacement field stored as half4 (x,y,z,pad) = uint2 per voxel (8B).

struct F3 { float x, y, z; };

__device__ __forceinline__ int swz_block(int bid) {
    // XCD-chunked bijective swizzle (NBLK % 8 == 0)
    const int chunk = NBLK / 8;
    return (bid & 7) * chunk + (bid >> 3);
}

__device__ __forceinline__ __half2 lerp2(__half2 a, __half2 b, __half2 w) {
    return __hfma2(w, __hsub2(b, a), a);   // v_pk_sub_f16 + v_pk_fma_f16
}

// u_new(p) = u(p) + trilinear_border(u, p + u(p)); border folded into weights.
// x- and y-lerps in packed fp16; z-lerp in f32.
__device__ __forceinline__ F3 step_compute(const uint2* __restrict__ un, int r) {
    int x = r & 127, y = (r >> 7) & 127, z = r >> 14;

    uint2 c = un[r];
    float2 cxy = __half22float2(*(const __half2*)&c.x);
    float  ucz = __low2float(*(const __half2*)&c.y);
    float ux = cxy.x, uy = cxy.y, uz = ucz;

    float gx = (float)x + ux, gy = (float)y + uy, gz = (float)z + uz;

    // clamp-to-border folded into [base, base+1] window + weights (v_med3)
    float gcx = fminf(fmaxf(gx, 0.f), 127.f);
    float gcy = fminf(fmaxf(gy, 0.f), 127.f);
    float gcz = fminf(fmaxf(gz, 0.f), 127.f);
    float xbf = fminf(floorf(gcx), 126.f);
    float ybf = fminf(floorf(gcy), 126.f);
    float zbf = fminf(floorf(gcz), 126.f);
    float wx = gcx - xbf, wy = gcy - ybf, wz = gcz - zbf;

    int base = (int)fmaf(zbf, 16384.f, fmaf(ybf, 128.f, xbf));

    const uint2* p00 = un + base;
    uint4 q00 = *(const uint4*)(p00);                  // (zb,   yb  ) x-pair
    uint4 q01 = *(const uint4*)(p00 + 128);            // (zb,   yb+1)
    uint4 q10 = *(const uint4*)(p00 + 16384);          // (zb+1, yb  )
    uint4 q11 = *(const uint4*)(p00 + 16384 + 128);    // (zb+1, yb+1)

    __half2 wx2 = __float2half2_rn(wx);
    __half2 wy2 = __float2half2_rn(wy);

    // x-lerp (packed fp16): per corner pair, (x,y) and (z,pad) lanes
    __half2 r00xy = lerp2(*(__half2*)&q00.x, *(__half2*)&q00.z, wx2);
    __half2 r00zp = lerp2(*(__half2*)&q00.y, *(__half2*)&q00.w, wx2);
    __half2 r01xy = lerp2(*(__half2*)&q01.x, *(__half2*)&q01.z, wx2);
    __half2 r01zp = lerp2(*(__half2*)&q01.y, *(__half2*)&q01.w, wx2);
    __half2 r10xy = lerp2(*(__half2*)&q10.x, *(__half2*)&q10.z, wx2);
    __half2 r10zp = lerp2(*(__half2*)&q10.y, *(__half2*)&q10.w, wx2);
    __half2 r11xy = lerp2(*(__half2*)&q11.x, *(__half2*)&q11.z, wx2);
    __half2 r11zp = lerp2(*(__half2*)&q11.y, *(__half2*)&q11.w, wx2);

    // y-lerp (packed fp16)
    __half2 s0xy = lerp2(r00xy, r01xy, wy2);
    __half2 s0zp = lerp2(r00zp, r01zp, wy2);
    __half2 s1xy = lerp2(r10xy, r11xy, wy2);
    __half2 s1zp = lerp2(r10zp, r11zp, wy2);

    // convert the two y-results, z-lerp in f32
    float2 s0 = __half22float2(s0xy);
    float  s0z = __low2float(s0zp);
    float2 s1 = __half22float2(s1xy);
    float  s1z = __low2float(s1zp);

    F3 o;
    o.x = ux + fmaf(wz, s1.x - s0.x, s0.x);
    o.y = uy + fmaf(wz, s1.y - s0.y, s0.y);
    o.z = uz + fmaf(wz, s1z - s0z, s0z);
    return o;
}

__device__ __forceinline__ uint2 pack_h4(F3 o) {
    __half2 hxy = __float22half2_rn(make_float2(o.x, o.y));
    __half2 hz  = __float22half2_rn(make_float2(o.z, 0.f));
    uint2 w;
    w.x = *(const unsigned int*)&hxy;
    w.y = *(const unsigned int*)&hz;
    return w;
}

// u0 = v / 4096, planar f32 -> interleaved half4
__global__ __launch_bounds__(256) void svf_init(const float* __restrict__ v,
                                                uint2* __restrict__ u) {
    int i = blockIdx.x * blockDim.x + threadIdx.x;   // over NVOX
    int n = i >> 21, r = i & (DHW - 1);
    const float* vn = v + (size_t)n * CDHW;
    F3 o;
    o.x = vn[r] * (1.0f / 4096.0f);
    o.y = vn[DHW + r] * (1.0f / 4096.0f);
    o.z = vn[2 * DHW + r] * (1.0f / 4096.0f);
    u[i] = pack_h4(o);
}

// interleaved half4 -> interleaved half4
__global__ __launch_bounds__(256) void svf_step(const uint2* __restrict__ uin,
                                                uint2* __restrict__ uout) {
    int i = swz_block(blockIdx.x) * 256 + threadIdx.x;   // over NVOX
    int n = i >> 21, r = i & (DHW - 1);
    uout[i] = pack_h4(step_compute(uin + (size_t)n * DHW, r));
}

// final step fused with epilogue: half4 u11 -> planar f32 T and disp_vox
__global__ __launch_bounds__(256) void svf_fused(const uint2* __restrict__ uin,
                                                 float* __restrict__ T,
                                                 float* __restrict__ Dp) {
    int i = swz_block(blockIdx.x) * 256 + threadIdx.x;
    int n = i >> 21, r = i & (DHW - 1);
    int x = r & 127, y = (r >> 7) & 127, z = r >> 14;
    F3 o = step_compute(uin + (size_t)n * DHW, r);
    float* Dn = Dp + (size_t)n * CDHW;
    Dn[r] = o.x;
    Dn[DHW + r] = o.y;
    Dn[2 * DHW + r] = o.z;
    float* Tn = T + (size_t)n * CDHW;
    Tn[r]           = -1.0f + (2.0f / 127.0f) * ((float)x + o.x);
    Tn[DHW + r]     = -1.0f + (2.0f / 127.0f) * ((float)y + o.y);
    Tn[2 * DHW + r] = -1.0f + (2.0f / 127.0f) * ((float)z + o.z);
}

// fallback: half4 -> planar f32 (step 11 without fusion)
__global__ __launch_bounds__(256) void svf_step_planar(const uint2* __restrict__ uin,
                                                       float* __restrict__ up) {
    int i = blockIdx.x * blockDim.x + threadIdx.x;
    int n = i >> 21, r = i & (DHW - 1);
    F3 o = step_compute(uin + (size_t)n * DHW, r);
    float* uon = up + (size_t)n * CDHW;
    uon[r] = o.x;
    uon[DHW + r] = o.y;
    uon[2 * DHW + r] = o.z;
}

// fallback epilogue: planar u12 -> transformation
__global__ __launch_bounds__(256) void svf_final(const float* __restrict__ u,
                                                 float* __restrict__ T) {
    int i = blockIdx.x * blockDim.x + threadIdx.x;   // over NCDHW
    int r = i & (DHW - 1);
    int c = (i >> 21) % 3;
    int coord = (c == 0) ? (r & 127) : (c == 1) ? ((r >> 7) & 127) : (r >> 14);
    T[i] = -1.0f + (2.0f / 127.0f) * ((float)coord + u[i]);
}

extern "C" void kernel_launch(void* const* d_in, const int* in_sizes, int n_in,
                              void* d_out, int out_size, void* d_ws, size_t ws_size,
                              hipStream_t stream) {
    const float* v = (const float*)d_in[0];
    float* out = (float*)d_out;
    const size_t bufbytes = (size_t)NVOX * 8;   // 33.5 MB

    if (ws_size >= bufbytes) {
        // A = T-half of d_out (as half4 buffer), B = d_ws.
        uint2* A = (uint2*)out;
        uint2* B = (uint2*)d_ws;
        svf_init<<<NBLK, 256, 0, stream>>>(v, A);
        // 11 ping-pong steps (s=0..10): even A->B, odd B->A; u11 ends in B.
        for (int s = 0; s <= 10; ++s) {
            const uint2* src = (s & 1) ? B : A;
            uint2* dst = (s & 1) ? A : B;
            svf_step<<<NBLK, 256, 0, stream>>>(src, dst);
        }
        // step 11 fused with epilogue: B (ws) -> both planar f32 outputs.
        svf_fused<<<NBLK, 256, 0, stream>>>(B, out, out + NCDHW);
    } else {
        // No usable ws: buffers inside d_out halves (each half 50.3MB > 33.5MB).
        uint2* A = (uint2*)out;            // T half
        uint2* B = (uint2*)(out + NCDHW);  // disp half
        svf_init<<<NBLK, 256, 0, stream>>>(v, B);
        // s even: B->A, s odd: A->B; after s=10, u11 in A (T half).
        for (int s = 0; s <= 10; ++s) {
            const uint2* src = (s & 1) ? A : B;
            uint2* dst = (s & 1) ? B : A;
            svf_step<<<NBLK, 256, 0, stream>>>(src, dst);
        }
        // step 11: A -> planar f32 u12 into disp half (no overlap with A).
        svf_step_planar<<<NBLK, 256, 0, stream>>>(A, out + NCDHW);
        // epilogue: disp half -> transformation half.
        svf_final<<<NCDHW / 256, 256, 0, stream>>>(out + NCDHW, out);
    }
}